// Round 14
// baseline (482.802 us; speedup 1.0000x reference)
//
#include <hip/hip_runtime.h>
#include <hip/hip_cooperative_groups.h>
#include <math.h>

namespace cg = cooperative_groups;

#define NN 100000
#define NB 391          // ceil(NN/256) buckets of 256 nodes
#define BT 8192         // edges per binning tile
#define CAP 12288       // per-bucket LDS sort capacity (avg bucket ~8192)

typedef float vfloat2 __attribute__((ext_vector_type(2)));
typedef short short8 __attribute__((ext_vector_type(8)));
typedef float floatx4 __attribute__((ext_vector_type(4)));

// float -> bf16 (RNE)
__device__ __forceinline__ unsigned short f2bf(float f) {
    unsigned int u = __float_as_uint(f);
    u += 0x7fffu + ((u >> 16) & 1u);
    return (unsigned short)(u >> 16);
}

// fp8 e4m3 (OCP on gfx950) encode/decode via HW cvt.
__device__ __forceinline__ unsigned char f2fp8(float f) {
    const int p = __builtin_amdgcn_cvt_pk_fp8_f32(f, f, 0, false);
    return (unsigned char)(p & 0xFF);
}
template <bool HI>
__device__ __forceinline__ vfloat2 fp8pk2(unsigned int w) {
    return __builtin_amdgcn_cvt_pk_f32_fp8((int)w, HI);
}

// ---------------------------------------------------------------------------
// Fused CSR build (cooperative): zero -> hist -> scan -> bin -> sort.
// Replaces 5 dispatches with 1; phases separated by grid.sync().
// LDS phase-aliased via POD union (59 KB -> 2 blocks/CU; 391 blocks co-resident).
// ---------------------------------------------------------------------------
union BuildSmem {
    struct { int lh[NB]; } hist;
    struct { int s[512]; } scan;
    struct {
        unsigned int stage[BT];
        unsigned short sbkt[BT];
        int lhist[512], lscan[512], lstart[512], gbase[512], lcur[512];
    } bin;
    struct { int stage[CAP]; int hist[256]; int lexcl[256]; int lcur[256]; } sort;
};

__global__ void __launch_bounds__(512)
build_csr_coop(const int* __restrict__ src, const int* __restrict__ dst,
               int* __restrict__ bcnt, int* __restrict__ boffs,
               int* __restrict__ bcursor, unsigned int* __restrict__ binned,
               int* __restrict__ ssrc, int* __restrict__ row_ptr,
               float* __restrict__ inv_deg, int n_nodes, int n_edges) {
    cg::grid_group grid = cg::this_grid();
    __shared__ BuildSmem u;
    const int t = threadIdx.x;
    const int nb = gridDim.x;

    // ---- phase 0: zero bcnt ----
    for (int i = blockIdx.x * 512 + t; i < NB; i += nb * 512) bcnt[i] = 0;
    grid.sync();

    // ---- phase 1: histogram (LDS-local, one flush per block) ----
    for (int i = t; i < NB; i += 512) u.hist.lh[i] = 0;
    __syncthreads();
    for (int e = blockIdx.x * 512 + t; e < n_edges; e += nb * 512)
        atomicAdd(&u.hist.lh[dst[e] >> 8], 1);
    __syncthreads();
    for (int i = t; i < NB; i += 512) {
        const int v = u.hist.lh[i];
        if (v) atomicAdd(&bcnt[i], v);
    }
    grid.sync();

    // ---- phase 2: exclusive scan (block 0 only) ----
    if (blockIdx.x == 0) {
        const int v = (t < NB) ? bcnt[t] : 0;
        u.scan.s[t] = v;
        __syncthreads();
        for (int off = 1; off < 512; off <<= 1) {
            const int tmp = (t >= off) ? u.scan.s[t - off] : 0;
            __syncthreads();
            u.scan.s[t] += tmp;
            __syncthreads();
        }
        const int excl = u.scan.s[t] - v;
        if (t <= NB) boffs[t] = excl;
        if (t < NB) bcursor[t] = excl;
    }
    grid.sync();

    // ---- phase 3: bin edges into 256-node dst buckets ----
    for (int tile = blockIdx.x; (long long)tile * BT < n_edges; tile += nb) {
        const int e0 = tile * BT;
        const int count = min(BT, n_edges - e0);
        u.bin.lhist[t] = 0;
        __syncthreads();
        for (int i = t; i < count; i += 512) atomicAdd(&u.bin.lhist[dst[e0 + i] >> 8], 1);
        __syncthreads();
        const int v = u.bin.lhist[t];
        u.bin.lscan[t] = v;
        __syncthreads();
        for (int off = 1; off < 512; off <<= 1) {
            const int tmp = (t >= off) ? u.bin.lscan[t - off] : 0;
            __syncthreads();
            u.bin.lscan[t] += tmp;
            __syncthreads();
        }
        const int excl = u.bin.lscan[t] - v;
        u.bin.lstart[t] = excl;
        u.bin.lcur[t] = excl;
        if (t < NB && v > 0) u.bin.gbase[t] = atomicAdd(&bcursor[t], v);
        __syncthreads();
        for (int i = t; i < count; i += 512) {
            const int d = dst[e0 + i];
            const int b = d >> 8;
            const int p = atomicAdd(&u.bin.lcur[b], 1);
            u.bin.stage[p] = (unsigned int)src[e0 + i] | ((unsigned int)(d & 255) << 17);
            u.bin.sbkt[p] = (unsigned short)b;
        }
        __syncthreads();
        for (int i = t; i < count; i += 512) {
            const int b = u.bin.sbkt[i];
            binned[u.bin.gbase[b] + (i - u.bin.lstart[b])] = u.bin.stage[i];
        }
        __syncthreads();
    }
    grid.sync();

    // ---- phase 4: per-bucket counting sort -> ssrc, row_ptr, inv_deg ----
    for (int b = blockIdx.x; b < NB; b += nb) {
        const int s0 = boffs[b], s1 = boffs[b + 1];
        const int count = s1 - s0;
        if (t < 256) u.sort.hist[t] = 0;
        __syncthreads();
        for (int i = t; i < count; i += 512)
            atomicAdd(&u.sort.hist[binned[s0 + i] >> 17], 1);
        __syncthreads();
        if (t < 256) u.sort.lexcl[t] = u.sort.hist[t];
        __syncthreads();
        for (int off = 1; off < 256; off <<= 1) {
            int tmp = 0;
            if (t < 256 && t >= off) tmp = u.sort.lexcl[t - off];
            __syncthreads();
            if (t < 256) u.sort.lexcl[t] += tmp;
            __syncthreads();
        }
        if (t < 256) {
            const int excl = u.sort.lexcl[t] - u.sort.hist[t];
            u.sort.lcur[t] = excl;
            const int n = (b << 8) + t;
            if (n < n_nodes) {
                row_ptr[n] = s0 + excl;
                inv_deg[n] = 1.0f / (float)max(u.sort.hist[t], 1);
            }
        }
        if (b == NB - 1 && t == 0) row_ptr[n_nodes] = n_edges;
        __syncthreads();
        for (int i = t; i < count; i += 512) {
            const unsigned int v = binned[s0 + i];
            const int p = atomicAdd(&u.sort.lcur[v >> 17], 1);
            if (p < CAP) u.sort.stage[p] = (int)(v & 0x1FFFFu);
        }
        __syncthreads();
        for (int i = t; i < count; i += 512) ssrc[s0 + i] = u.sort.stage[i];
        __syncthreads();
    }
}

// ---------------------------------------------------------------------------
// MFMA dual MLP (layers 1-2):
//   y[n, 0..CL)  = h @ Wl          (fp8 out)
//   z[n, 0..CR)  = h @ Wr + bias   (f32 out)
// h = FUSE_IN ? relu(in0 + in1) : in0, computed during staging.
// ---------------------------------------------------------------------------
template <int D_IN, int CL, int CR, int NPB, int FUSE_IN>
__global__ void __launch_bounds__(256)
mlp_mfma_kernel(const float* __restrict__ in0,
                const float* __restrict__ in1,
                const float* __restrict__ Wl,
                const float* __restrict__ Wr,
                const float* __restrict__ bias,
                unsigned char* __restrict__ yout,
                float* __restrict__ zout,
                int n_nodes) {
    constexpr int COLS = CL + CR;
    constexpr int CT = COLS / 16;
    constexpr int KT = D_IN / 32;
    constexpr int NT = NPB / 16;
    constexpr int KG = D_IN / 8;
    __shared__ short sA[NT * KT * 64 * 8];
    __shared__ short sB[CT * KT * 64 * 8];
    __shared__ float sBias[CR];
    const int t = threadIdx.x;
    const int node0 = blockIdx.x * NPB;

    for (int i = t; i < NPB * KG; i += 256) {
        const int nl = i / KG, kg = i % KG;
        const int n = node0 + nl;
        float v[8];
        if (n < n_nodes) {
            const float4* p = (const float4*)(in0 + (long long)n * D_IN + kg * 8);
            float4 a0 = p[0], a1 = p[1];
            if (FUSE_IN) {
                const float4* q = (const float4*)(in1 + (long long)n * D_IN + kg * 8);
                const float4 b0 = q[0], b1 = q[1];
                a0.x = fmaxf(a0.x + b0.x, 0.f); a0.y = fmaxf(a0.y + b0.y, 0.f);
                a0.z = fmaxf(a0.z + b0.z, 0.f); a0.w = fmaxf(a0.w + b0.w, 0.f);
                a1.x = fmaxf(a1.x + b1.x, 0.f); a1.y = fmaxf(a1.y + b1.y, 0.f);
                a1.z = fmaxf(a1.z + b1.z, 0.f); a1.w = fmaxf(a1.w + b1.w, 0.f);
            }
            v[0] = a0.x; v[1] = a0.y; v[2] = a0.z; v[3] = a0.w;
            v[4] = a1.x; v[5] = a1.y; v[6] = a1.z; v[7] = a1.w;
        } else {
#pragma unroll
            for (int j = 0; j < 8; ++j) v[j] = 0.f;
        }
        short8 s;
#pragma unroll
        for (int j = 0; j < 8; ++j) s[j] = (short)f2bf(v[j]);
        const int nt = nl >> 4, m = nl & 15, kt = kg >> 2, quad = kg & 3;
        ((short8*)sA)[(nt * KT + kt) * 64 + quad * 16 + m] = s;
    }
    for (int i = t; i < CT * KT * 64; i += 256) {
        const int ct = i / (KT * 64);
        const int rem = i % (KT * 64);
        const int kt = rem / 64, L = rem % 64;
        const int c = ct * 16 + (L & 15);
        const int k0 = kt * 32 + (L >> 4) * 8;
        short8 s;
#pragma unroll
        for (int j = 0; j < 8; ++j) {
            const int k = k0 + j;
            const float w = (c < CL) ? Wl[k * CL + c] : Wr[k * CR + (c - CL)];
            s[j] = (short)f2bf(w);
        }
        ((short8*)sB)[i] = s;
    }
    for (int i = t; i < CR; i += 256) sBias[i] = bias[i];
    __syncthreads();

    const int w = t >> 6, lane = t & 63;
    short8 Bf[CT][KT];
#pragma unroll
    for (int ct = 0; ct < CT; ++ct)
#pragma unroll
        for (int kt = 0; kt < KT; ++kt)
            Bf[ct][kt] = ((short8*)sB)[(ct * KT + kt) * 64 + lane];
    const int col = lane & 15, quad = lane >> 4;
#pragma unroll
    for (int nti = 0; nti < NT / 4; ++nti) {
        const int nt = w * (NT / 4) + nti;
        short8 A[KT];
#pragma unroll
        for (int kt = 0; kt < KT; ++kt)
            A[kt] = ((short8*)sA)[(nt * KT + kt) * 64 + lane];
        const int nodeb = node0 + nt * 16 + quad * 4;
#pragma unroll
        for (int ct = 0; ct < CT; ++ct) {
            floatx4 acc = {0.f, 0.f, 0.f, 0.f};
#pragma unroll
            for (int kt = 0; kt < KT; ++kt)
                acc = __builtin_amdgcn_mfma_f32_16x16x32_bf16(A[kt], Bf[ct][kt], acc, 0, 0, 0);
            const int gc = ct * 16 + col;
#pragma unroll
            for (int r = 0; r < 4; ++r) {
                const int node = nodeb + r;
                if (node < n_nodes) {
                    if (gc < CL) yout[(long long)node * CL + gc] = f2fp8(acc[r]);
                    else zout[(long long)node * CR + (gc - CL)] = acc[r] + sBias[gc - CL];
                }
            }
        }
    }
}

// ---------------------------------------------------------------------------
// Layer-3 MLP: one thread per node. h = relu(mean2+z2);
// y3[n] = h@W3l, z3[n] = h@W3r + b3.
// ---------------------------------------------------------------------------
template <int D_IN>
__global__ void __launch_bounds__(256)
mlp3_kernel(const float* __restrict__ mean,
            const float* __restrict__ z,
            const float* __restrict__ W3l,
            const float* __restrict__ W3r,
            const float* __restrict__ b3,
            float* __restrict__ y,
            float* __restrict__ z3, int n_nodes) {
    __shared__ float swl[D_IN], swr[D_IN];
    const int t = threadIdx.x;
    if (t < D_IN) { swl[t] = W3l[t]; swr[t] = W3r[t]; }
    __syncthreads();
    const int n = blockIdx.x * 256 + t;
    if (n >= n_nodes) return;
    const float4* pm = (const float4*)(mean + (long long)n * D_IN);
    const float4* pz = (const float4*)(z + (long long)n * D_IN);
    float accl = 0.f, accr = 0.f;
#pragma unroll
    for (int q = 0; q < D_IN / 4; ++q) {
        const float4 m4 = pm[q];
        const float4 z4 = pz[q];
        const float h0 = fmaxf(m4.x + z4.x, 0.f);
        const float h1 = fmaxf(m4.y + z4.y, 0.f);
        const float h2 = fmaxf(m4.z + z4.z, 0.f);
        const float h3 = fmaxf(m4.w + z4.w, 0.f);
        accl += h0 * swl[4 * q] + h1 * swl[4 * q + 1] + h2 * swl[4 * q + 2] + h3 * swl[4 * q + 3];
        accr += h0 * swr[4 * q] + h1 * swr[4 * q + 1] + h2 * swr[4 * q + 2] + h3 * swr[4 * q + 3];
    }
    y[n] = accl;
    z3[n] = accr + b3[0];
}

// ---------------------------------------------------------------------------
// gather-side mean over fp8 rows (proven round-10 version: unroll 4, VGPR 48).
// ---------------------------------------------------------------------------
template <int D>
__global__ void agg_mean_fp8_kernel(const unsigned int* __restrict__ yb,
                                    const int* __restrict__ row_ptr,
                                    const int* __restrict__ ssrc,
                                    const float* __restrict__ inv_deg,
                                    float* __restrict__ mean, int n_nodes) {
    constexpr int G = D / 16;
    constexpr int NPB = 256 / G;
    const int g = threadIdx.x / G;
    const int lane = threadIdx.x % G;
    const int n = blockIdx.x * NPB + g;
    if (n >= n_nodes) return;
    const int s0 = row_ptr[n], s1 = row_ptr[n + 1];
    const uint4* yv = (const uint4*)yb;          // row stride = G uint4
    float acc[16];
#pragma unroll
    for (int i = 0; i < 16; ++i) acc[i] = 0.f;
    int e = s0;
    for (; e + 4 <= s1; e += 4) {
        uint4 v[4];
        v[0] = yv[(long long)ssrc[e] * G + lane];
        v[1] = yv[(long long)ssrc[e + 1] * G + lane];
        v[2] = yv[(long long)ssrc[e + 2] * G + lane];
        v[3] = yv[(long long)ssrc[e + 3] * G + lane];
#pragma unroll
        for (int q = 0; q < 4; ++q) {
            const unsigned int wx = v[q].x, wy = v[q].y, wz = v[q].z, ww = v[q].w;
            vfloat2 p;
            p = fp8pk2<false>(wx); acc[0]  += p.x; acc[1]  += p.y;
            p = fp8pk2<true>(wx);  acc[2]  += p.x; acc[3]  += p.y;
            p = fp8pk2<false>(wy); acc[4]  += p.x; acc[5]  += p.y;
            p = fp8pk2<true>(wy);  acc[6]  += p.x; acc[7]  += p.y;
            p = fp8pk2<false>(wz); acc[8]  += p.x; acc[9]  += p.y;
            p = fp8pk2<true>(wz);  acc[10] += p.x; acc[11] += p.y;
            p = fp8pk2<false>(ww); acc[12] += p.x; acc[13] += p.y;
            p = fp8pk2<true>(ww);  acc[14] += p.x; acc[15] += p.y;
        }
    }
    for (; e < s1; ++e) {
        const uint4 v = yv[(long long)ssrc[e] * G + lane];
        vfloat2 p;
        p = fp8pk2<false>(v.x); acc[0]  += p.x; acc[1]  += p.y;
        p = fp8pk2<true>(v.x);  acc[2]  += p.x; acc[3]  += p.y;
        p = fp8pk2<false>(v.y); acc[4]  += p.x; acc[5]  += p.y;
        p = fp8pk2<true>(v.y);  acc[6]  += p.x; acc[7]  += p.y;
        p = fp8pk2<false>(v.z); acc[8]  += p.x; acc[9]  += p.y;
        p = fp8pk2<true>(v.z);  acc[10] += p.x; acc[11] += p.y;
        p = fp8pk2<false>(v.w); acc[12] += p.x; acc[13] += p.y;
        p = fp8pk2<true>(v.w);  acc[14] += p.x; acc[15] += p.y;
    }
    const float inv = inv_deg[n];
    float4* mv = (float4*)mean;
    const long long base = (long long)n * (D / 4) + lane * 4;
#pragma unroll
    for (int q = 0; q < 4; ++q)
        mv[base + q] = make_float4(acc[4 * q] * inv, acc[4 * q + 1] * inv,
                                   acc[4 * q + 2] * inv, acc[4 * q + 3] * inv);
}

// D == 1 agg + sigmoid epilogue: out[n] = sigmoid(mean3 + z3)
__global__ void agg_d1_sig_kernel(const float* __restrict__ y,
                                  const int* __restrict__ row_ptr,
                                  const int* __restrict__ ssrc,
                                  const float* __restrict__ inv_deg,
                                  const float* __restrict__ z3,
                                  float* __restrict__ out, int n_nodes) {
    const int wave = threadIdx.x >> 6;
    const int lane = threadIdx.x & 63;
    const int n = blockIdx.x * 4 + wave;
    if (n >= n_nodes) return;
    const int s0 = row_ptr[n], s1 = row_ptr[n + 1];
    float acc = 0.f;
    for (int e = s0 + lane; e < s1; e += 64) acc += y[ssrc[e]];
    for (int off = 32; off > 0; off >>= 1) acc += __shfl_down(acc, off, 64);
    if (lane == 0) {
        const float v = acc * inv_deg[n] + z3[n];
        out[n] = 1.0f / (1.0f + expf(-v));
    }
}

extern "C" void kernel_launch(void* const* d_in, const int* in_sizes, int n_in,
                              void* d_out, int out_size, void* d_ws, size_t ws_size,
                              hipStream_t stream) {
    const float* x = (const float*)d_in[0];
    const int* edge_index = (const int*)d_in[1];
    const float* W1l = (const float*)d_in[2];
    const float* b1  = (const float*)d_in[3];
    const float* W1r = (const float*)d_in[4];
    const float* W2l = (const float*)d_in[5];
    const float* b2  = (const float*)d_in[6];
    const float* W2r = (const float*)d_in[7];
    const float* W3l = (const float*)d_in[8];
    const float* b3  = (const float*)d_in[9];
    const float* W3r = (const float*)d_in[10];
    float* out = (float*)d_out;

    const int E = in_sizes[1] / 2;
    const int* src = edge_index;
    const int* dst = edge_index + E;

    // floats: bufY[32N] | meanB[64N] | z1[64N] | z2[32N] | z3[N] | inv_deg[N]
    // ints:   bcnt[NB] | boffs[NB+1] | bcursor[NB] | row_ptr[N+1] | ssrc[E]
    // binned[E] aliases z1 (dead after build)
    float* bufY    = (float*)d_ws;
    float* meanB   = bufY + 32LL * NN;
    float* z1      = meanB + 64LL * NN;
    float* z2      = z1 + 64LL * NN;
    float* z3      = z2 + 32LL * NN;
    float* inv_deg = z3 + NN;
    int* bcnt      = (int*)(inv_deg + NN);
    int* boffs     = bcnt + NB;
    int* bcursor   = boffs + NB + 1;
    int* row_ptr   = bcursor + NB;
    int* ssrc      = row_ptr + NN + 1;
    unsigned int* binned = (unsigned int*)z1;

    // ---- fused CSR build (1 cooperative dispatch replaces 5) ----
    {
        int nn = NN, e = E;
        const int* a_src = src;
        const int* a_dst = dst;
        void* args[] = {(void*)&a_src, (void*)&a_dst, (void*)&bcnt, (void*)&boffs,
                        (void*)&bcursor, (void*)&binned, (void*)&ssrc,
                        (void*)&row_ptr, (void*)&inv_deg, (void*)&nn, (void*)&e};
        (void)hipLaunchCooperativeKernel((void*)build_csr_coop, dim3(NB), dim3(512),
                                         args, 0, stream);
    }

    // ---- layer 1: y1 = x@W1l (fp8), z1 = x@W1r + b1 (MFMA) ----
    mlp_mfma_kernel<64, 64, 64, 128, 0><<<(NN + 127) / 128, 256, 0, stream>>>(
        x, nullptr, W1l, W1r, b1, (unsigned char*)bufY, z1, NN);
    agg_mean_fp8_kernel<64><<<(NN + 63) / 64, 256, 0, stream>>>(
        (const unsigned int*)bufY, row_ptr, ssrc, inv_deg, meanB, NN);

    // ---- layer 2: h1 = relu(mean1+z1) fused; y2 fp8, z2 (MFMA) ----
    mlp_mfma_kernel<64, 32, 32, 128, 1><<<(NN + 127) / 128, 256, 0, stream>>>(
        meanB, z1, W2l, W2r, b2, (unsigned char*)bufY, z2, NN);
    agg_mean_fp8_kernel<32><<<(NN + 127) / 128, 256, 0, stream>>>(
        (const unsigned int*)bufY, row_ptr, ssrc, inv_deg, meanB, NN);

    // ---- layer 3: h2 = relu(mean2+z2); y3 f32, z3 ----
    float* y3 = bufY;  // y2 dead after agg32
    mlp3_kernel<32><<<(NN + 255) / 256, 256, 0, stream>>>(
        meanB, z2, W3l, W3r, b3, y3, z3, NN);

    // ---- final: mean3 + z3 -> sigmoid ----
    agg_d1_sig_kernel<<<(NN + 3) / 4, 256, 0, stream>>>(
        y3, row_ptr, ssrc, inv_deg, z3, out, NN);
}

// Round 15
// 308.709 us; speedup vs baseline: 1.5639x; 1.5639x over previous
//
#include <hip/hip_runtime.h>
#include <math.h>

#define NN 100000
#define NB 391          // ceil(NN/256) buckets of 256 nodes
#define BT 8192         // edges per binning tile
#define CAP 12288       // per-bucket LDS sort capacity (avg bucket ~8192)

typedef float vfloat2 __attribute__((ext_vector_type(2)));
typedef short short8 __attribute__((ext_vector_type(8)));
typedef float floatx4 __attribute__((ext_vector_type(4)));

// float -> bf16 (RNE)
__device__ __forceinline__ unsigned short f2bf(float f) {
    unsigned int u = __float_as_uint(f);
    u += 0x7fffu + ((u >> 16) & 1u);
    return (unsigned short)(u >> 16);
}

// fp8 e4m3 (OCP on gfx950) encode/decode via HW cvt.
__device__ __forceinline__ unsigned char f2fp8(float f) {
    const int p = __builtin_amdgcn_cvt_pk_fp8_f32(f, f, 0, false);
    return (unsigned char)(p & 0xFF);
}
template <bool HI>
__device__ __forceinline__ vfloat2 fp8pk2(unsigned int w) {
    return __builtin_amdgcn_cvt_pk_f32_fp8((int)w, HI);
}

// ---------------------------------------------------------------------------
// MFMA dual MLP (layers 1-2):
//   y[n, 0..CL)  = h @ Wl          (fp8 out)
//   z[n, 0..CR)  = h @ Wr + bias   (f32 out)
// h = FUSE_IN ? relu(in0 + in1) : in0, computed during staging.
// ---------------------------------------------------------------------------
template <int D_IN, int CL, int CR, int NPB, int FUSE_IN>
__global__ void __launch_bounds__(256)
mlp_mfma_kernel(const float* __restrict__ in0,
                const float* __restrict__ in1,
                const float* __restrict__ Wl,
                const float* __restrict__ Wr,
                const float* __restrict__ bias,
                unsigned char* __restrict__ yout,
                float* __restrict__ zout,
                int n_nodes) {
    constexpr int COLS = CL + CR;
    constexpr int CT = COLS / 16;
    constexpr int KT = D_IN / 32;
    constexpr int NT = NPB / 16;
    constexpr int KG = D_IN / 8;
    __shared__ short sA[NT * KT * 64 * 8];
    __shared__ short sB[CT * KT * 64 * 8];
    __shared__ float sBias[CR];
    const int t = threadIdx.x;
    const int node0 = blockIdx.x * NPB;

    for (int i = t; i < NPB * KG; i += 256) {
        const int nl = i / KG, kg = i % KG;
        const int n = node0 + nl;
        float v[8];
        if (n < n_nodes) {
            const float4* p = (const float4*)(in0 + (long long)n * D_IN + kg * 8);
            float4 a0 = p[0], a1 = p[1];
            if (FUSE_IN) {
                const float4* q = (const float4*)(in1 + (long long)n * D_IN + kg * 8);
                const float4 b0 = q[0], b1 = q[1];
                a0.x = fmaxf(a0.x + b0.x, 0.f); a0.y = fmaxf(a0.y + b0.y, 0.f);
                a0.z = fmaxf(a0.z + b0.z, 0.f); a0.w = fmaxf(a0.w + b0.w, 0.f);
                a1.x = fmaxf(a1.x + b1.x, 0.f); a1.y = fmaxf(a1.y + b1.y, 0.f);
                a1.z = fmaxf(a1.z + b1.z, 0.f); a1.w = fmaxf(a1.w + b1.w, 0.f);
            }
            v[0] = a0.x; v[1] = a0.y; v[2] = a0.z; v[3] = a0.w;
            v[4] = a1.x; v[5] = a1.y; v[6] = a1.z; v[7] = a1.w;
        } else {
#pragma unroll
            for (int j = 0; j < 8; ++j) v[j] = 0.f;
        }
        short8 s;
#pragma unroll
        for (int j = 0; j < 8; ++j) s[j] = (short)f2bf(v[j]);
        const int nt = nl >> 4, m = nl & 15, kt = kg >> 2, quad = kg & 3;
        ((short8*)sA)[(nt * KT + kt) * 64 + quad * 16 + m] = s;
    }
    for (int i = t; i < CT * KT * 64; i += 256) {
        const int ct = i / (KT * 64);
        const int rem = i % (KT * 64);
        const int kt = rem / 64, L = rem % 64;
        const int c = ct * 16 + (L & 15);
        const int k0 = kt * 32 + (L >> 4) * 8;
        short8 s;
#pragma unroll
        for (int j = 0; j < 8; ++j) {
            const int k = k0 + j;
            const float w = (c < CL) ? Wl[k * CL + c] : Wr[k * CR + (c - CL)];
            s[j] = (short)f2bf(w);
        }
        ((short8*)sB)[i] = s;
    }
    for (int i = t; i < CR; i += 256) sBias[i] = bias[i];
    __syncthreads();

    const int w = t >> 6, lane = t & 63;
    short8 Bf[CT][KT];
#pragma unroll
    for (int ct = 0; ct < CT; ++ct)
#pragma unroll
        for (int kt = 0; kt < KT; ++kt)
            Bf[ct][kt] = ((short8*)sB)[(ct * KT + kt) * 64 + lane];
    const int col = lane & 15, quad = lane >> 4;
#pragma unroll
    for (int nti = 0; nti < NT / 4; ++nti) {
        const int nt = w * (NT / 4) + nti;
        short8 A[KT];
#pragma unroll
        for (int kt = 0; kt < KT; ++kt)
            A[kt] = ((short8*)sA)[(nt * KT + kt) * 64 + lane];
        const int nodeb = node0 + nt * 16 + quad * 4;
#pragma unroll
        for (int ct = 0; ct < CT; ++ct) {
            floatx4 acc = {0.f, 0.f, 0.f, 0.f};
#pragma unroll
            for (int kt = 0; kt < KT; ++kt)
                acc = __builtin_amdgcn_mfma_f32_16x16x32_bf16(A[kt], Bf[ct][kt], acc, 0, 0, 0);
            const int gc = ct * 16 + col;
#pragma unroll
            for (int r = 0; r < 4; ++r) {
                const int node = nodeb + r;
                if (node < n_nodes) {
                    if (gc < CL) yout[(long long)node * CL + gc] = f2fp8(acc[r]);
                    else zout[(long long)node * CR + (gc - CL)] = acc[r] + sBias[gc - CL];
                }
            }
        }
    }
}

// ---------------------------------------------------------------------------
// Layer-3 MLP: one thread per node. h = relu(mean2+z2);
// y3[n] = h@W3l, z3[n] = h@W3r + b3.
// ---------------------------------------------------------------------------
template <int D_IN>
__global__ void __launch_bounds__(256)
mlp3_kernel(const float* __restrict__ mean,
            const float* __restrict__ z,
            const float* __restrict__ W3l,
            const float* __restrict__ W3r,
            const float* __restrict__ b3,
            float* __restrict__ y,
            float* __restrict__ z3, int n_nodes) {
    __shared__ float swl[D_IN], swr[D_IN];
    const int t = threadIdx.x;
    if (t < D_IN) { swl[t] = W3l[t]; swr[t] = W3r[t]; }
    __syncthreads();
    const int n = blockIdx.x * 256 + t;
    if (n >= n_nodes) return;
    const float4* pm = (const float4*)(mean + (long long)n * D_IN);
    const float4* pz = (const float4*)(z + (long long)n * D_IN);
    float accl = 0.f, accr = 0.f;
#pragma unroll
    for (int q = 0; q < D_IN / 4; ++q) {
        const float4 m4 = pm[q];
        const float4 z4 = pz[q];
        const float h0 = fmaxf(m4.x + z4.x, 0.f);
        const float h1 = fmaxf(m4.y + z4.y, 0.f);
        const float h2 = fmaxf(m4.z + z4.z, 0.f);
        const float h3 = fmaxf(m4.w + z4.w, 0.f);
        accl += h0 * swl[4 * q] + h1 * swl[4 * q + 1] + h2 * swl[4 * q + 2] + h3 * swl[4 * q + 3];
        accr += h0 * swr[4 * q] + h1 * swr[4 * q + 1] + h2 * swr[4 * q + 2] + h3 * swr[4 * q + 3];
    }
    y[n] = accl;
    z3[n] = accr + b3[0];
}

// final epilogue: out = sigmoid(mean + z)
__global__ void sigmoid_out_kernel(const float* __restrict__ mean,
                                   const float* __restrict__ z,
                                   float* __restrict__ out, int n) {
    const int i = blockIdx.x * 256 + threadIdx.x;
    if (i < n) out[i] = 1.0f / (1.0f + expf(-(mean[i] + z[i])));
}

// ---------------------------------------------------------------------------
// gather-side mean over fp8 rows (proven: unroll 4, VGPR 48).
// G = D/16 lanes/node; uint4 = 16 fp8.
// ---------------------------------------------------------------------------
template <int D>
__global__ void agg_mean_fp8_kernel(const unsigned int* __restrict__ yb,
                                    const int* __restrict__ row_ptr,
                                    const int* __restrict__ ssrc,
                                    const float* __restrict__ inv_deg,
                                    float* __restrict__ mean, int n_nodes) {
    constexpr int G = D / 16;
    constexpr int NPB = 256 / G;
    const int g = threadIdx.x / G;
    const int lane = threadIdx.x % G;
    const int n = blockIdx.x * NPB + g;
    if (n >= n_nodes) return;
    const int s0 = row_ptr[n], s1 = row_ptr[n + 1];
    const uint4* yv = (const uint4*)yb;          // row stride = G uint4
    float acc[16];
#pragma unroll
    for (int i = 0; i < 16; ++i) acc[i] = 0.f;
    int e = s0;
    for (; e + 4 <= s1; e += 4) {
        uint4 v[4];
        v[0] = yv[(long long)ssrc[e] * G + lane];
        v[1] = yv[(long long)ssrc[e + 1] * G + lane];
        v[2] = yv[(long long)ssrc[e + 2] * G + lane];
        v[3] = yv[(long long)ssrc[e + 3] * G + lane];
#pragma unroll
        for (int q = 0; q < 4; ++q) {
            const unsigned int wx = v[q].x, wy = v[q].y, wz = v[q].z, ww = v[q].w;
            vfloat2 p;
            p = fp8pk2<false>(wx); acc[0]  += p.x; acc[1]  += p.y;
            p = fp8pk2<true>(wx);  acc[2]  += p.x; acc[3]  += p.y;
            p = fp8pk2<false>(wy); acc[4]  += p.x; acc[5]  += p.y;
            p = fp8pk2<true>(wy);  acc[6]  += p.x; acc[7]  += p.y;
            p = fp8pk2<false>(wz); acc[8]  += p.x; acc[9]  += p.y;
            p = fp8pk2<true>(wz);  acc[10] += p.x; acc[11] += p.y;
            p = fp8pk2<false>(ww); acc[12] += p.x; acc[13] += p.y;
            p = fp8pk2<true>(ww);  acc[14] += p.x; acc[15] += p.y;
        }
    }
    for (; e < s1; ++e) {
        const uint4 v = yv[(long long)ssrc[e] * G + lane];
        vfloat2 p;
        p = fp8pk2<false>(v.x); acc[0]  += p.x; acc[1]  += p.y;
        p = fp8pk2<true>(v.x);  acc[2]  += p.x; acc[3]  += p.y;
        p = fp8pk2<false>(v.y); acc[4]  += p.x; acc[5]  += p.y;
        p = fp8pk2<true>(v.y);  acc[6]  += p.x; acc[7]  += p.y;
        p = fp8pk2<false>(v.z); acc[8]  += p.x; acc[9]  += p.y;
        p = fp8pk2<true>(v.z);  acc[10] += p.x; acc[11] += p.y;
        p = fp8pk2<false>(v.w); acc[12] += p.x; acc[13] += p.y;
        p = fp8pk2<true>(v.w);  acc[14] += p.x; acc[15] += p.y;
    }
    const float inv = inv_deg[n];
    float4* mv = (float4*)mean;
    const long long base = (long long)n * (D / 4) + lane * 4;
#pragma unroll
    for (int q = 0; q < 4; ++q)
        mv[base + q] = make_float4(acc[4 * q] * inv, acc[4 * q + 1] * inv,
                                   acc[4 * q + 2] * inv, acc[4 * q + 3] * inv);
}

// D == 1 (fp32): one wave per node, shuffle reduction
__global__ void agg_mean_d1_kernel(const float* __restrict__ y,
                                   const int* __restrict__ row_ptr,
                                   const int* __restrict__ ssrc,
                                   const float* __restrict__ inv_deg,
                                   float* __restrict__ mean, int n_nodes) {
    const int wave = threadIdx.x >> 6;
    const int lane = threadIdx.x & 63;
    const int n = blockIdx.x * 4 + wave;
    if (n >= n_nodes) return;
    const int s0 = row_ptr[n], s1 = row_ptr[n + 1];
    float acc = 0.f;
    for (int e = s0 + lane; e < s1; e += 64) acc += y[ssrc[e]];
    for (int off = 32; off > 0; off >>= 1) acc += __shfl_down(acc, off, 64);
    if (lane == 0) mean[n] = acc * inv_deg[n];
}

// ---------------------------------------------------------------------------
// bucket histogram
// ---------------------------------------------------------------------------
__global__ void bucket_hist_kernel(const int* __restrict__ dst,
                                   int* __restrict__ bcnt, int n_edges) {
    __shared__ int lh[NB];
    for (int i = threadIdx.x; i < NB; i += 256) lh[i] = 0;
    __syncthreads();
    const int stride = gridDim.x * 256;
    for (int i = blockIdx.x * 256 + threadIdx.x; i < n_edges; i += stride)
        atomicAdd(&lh[dst[i] >> 8], 1);
    __syncthreads();
    for (int i = threadIdx.x; i < NB; i += 256)
        if (lh[i]) atomicAdd(&bcnt[i], lh[i]);
}

// ---------------------------------------------------------------------------
// single-block scan: boffs = exclusive scan of bcnt; bcursor = boffs
// ---------------------------------------------------------------------------
__global__ void __launch_bounds__(512)
bucket_scan_kernel(const int* __restrict__ bcnt, int* __restrict__ boffs,
                   int* __restrict__ bcursor) {
    __shared__ int s[512];
    const int t = threadIdx.x;
    const int v = (t < NB) ? bcnt[t] : 0;
    s[t] = v;
    __syncthreads();
    for (int off = 1; off < 512; off <<= 1) {
        const int tmp = (t >= off) ? s[t - off] : 0;
        __syncthreads();
        s[t] += tmp;
        __syncthreads();
    }
    const int excl = s[t] - v;
    if (t <= NB) boffs[t] = excl;
    if (t < NB) bcursor[t] = excl;
}

// ---------------------------------------------------------------------------
// binning: pack edges (src | dstLocal<<17) grouped by 256-node dst bucket.
// ---------------------------------------------------------------------------
__global__ void __launch_bounds__(512)
bin_edges_kernel(const int* __restrict__ src, const int* __restrict__ dst,
                 int* __restrict__ bcursor, unsigned int* __restrict__ binned,
                 int n_edges) {
    __shared__ unsigned int stage[BT];
    __shared__ unsigned short sbkt[BT];
    __shared__ int lhist[512], lscan[512], lstart[512], gbase[512], lcur[512];
    const int t = threadIdx.x;
    const int e0 = blockIdx.x * BT;
    const int count = min(BT, n_edges - e0);
    lhist[t] = 0;
    __syncthreads();
    for (int i = t; i < count; i += 512) atomicAdd(&lhist[dst[e0 + i] >> 8], 1);
    __syncthreads();
    const int v = lhist[t];
    lscan[t] = v;
    __syncthreads();
    for (int off = 1; off < 512; off <<= 1) {
        const int tmp = (t >= off) ? lscan[t - off] : 0;
        __syncthreads();
        lscan[t] += tmp;
        __syncthreads();
    }
    const int excl = lscan[t] - v;
    lstart[t] = excl;
    lcur[t] = excl;
    if (t < NB && v > 0) gbase[t] = atomicAdd(&bcursor[t], v);
    __syncthreads();
    for (int i = t; i < count; i += 512) {
        const int d = dst[e0 + i];
        const int b = d >> 8;
        const int p = atomicAdd(&lcur[b], 1);
        stage[p] = (unsigned int)src[e0 + i] | ((unsigned int)(d & 255) << 17);
        sbkt[p] = (unsigned short)b;
    }
    __syncthreads();
    for (int i = t; i < count; i += 512) {
        const int b = sbkt[i];
        binned[gbase[b] + (i - lstart[b])] = stage[i];
    }
}

// ---------------------------------------------------------------------------
// per-bucket counting sort -> full CSR (ssrc, row_ptr, inv_deg).
// ---------------------------------------------------------------------------
__global__ void __launch_bounds__(1024)
csr_sort_kernel(const unsigned int* __restrict__ binned,
                const int* __restrict__ boffs,
                int* __restrict__ ssrc, int* __restrict__ row_ptr,
                float* __restrict__ inv_deg, int n_nodes, int n_edges) {
    __shared__ int stage[CAP];
    __shared__ int hist[256];
    __shared__ int lexcl[256];
    __shared__ int lcur[256];
    const int t = threadIdx.x;
    const int b = blockIdx.x;
    const int s0 = boffs[b], s1 = boffs[b + 1];
    const int count = s1 - s0;
    if (t < 256) hist[t] = 0;
    __syncthreads();
    for (int i = t; i < count; i += 1024)
        atomicAdd(&hist[binned[s0 + i] >> 17], 1);
    __syncthreads();
    if (t < 256) lexcl[t] = hist[t];
    __syncthreads();
    for (int off = 1; off < 256; off <<= 1) {
        int tmp = 0;
        if (t < 256 && t >= off) tmp = lexcl[t - off];
        __syncthreads();
        if (t < 256) lexcl[t] += tmp;
        __syncthreads();
    }
    if (t < 256) {
        const int excl = lexcl[t] - hist[t];
        lcur[t] = excl;
        const int n = (b << 8) + t;
        if (n < n_nodes) {
            row_ptr[n] = s0 + excl;
            inv_deg[n] = 1.0f / (float)max(hist[t], 1);
        }
    }
    if (b == NB - 1 && t == 0) row_ptr[n_nodes] = n_edges;
    __syncthreads();
    for (int i = t; i < count; i += 1024) {
        const unsigned int v = binned[s0 + i];
        const int p = atomicAdd(&lcur[v >> 17], 1);
        if (p < CAP) stage[p] = (int)(v & 0x1FFFFu);
    }
    __syncthreads();
    for (int i = t; i < count; i += 1024) ssrc[s0 + i] = stage[i];
}

extern "C" void kernel_launch(void* const* d_in, const int* in_sizes, int n_in,
                              void* d_out, int out_size, void* d_ws, size_t ws_size,
                              hipStream_t stream) {
    const float* x = (const float*)d_in[0];
    const int* edge_index = (const int*)d_in[1];
    const float* W1l = (const float*)d_in[2];
    const float* b1  = (const float*)d_in[3];
    const float* W1r = (const float*)d_in[4];
    const float* W2l = (const float*)d_in[5];
    const float* b2  = (const float*)d_in[6];
    const float* W2r = (const float*)d_in[7];
    const float* W3l = (const float*)d_in[8];
    const float* b3  = (const float*)d_in[9];
    const float* W3r = (const float*)d_in[10];
    float* out = (float*)d_out;

    const int E = in_sizes[1] / 2;
    const int* src = edge_index;
    const int* dst = edge_index + E;

    // floats: bufY[32N] | meanB[64N] | z1[64N] | z2[32N] | z3[N] | inv_deg[N]
    // ints:   bcnt[NB] | boffs[NB+1] | bcursor[NB] | row_ptr[N+1] | ssrc[E]
    // binned[E] aliases z1 (dead after csr_sort)
    float* bufY    = (float*)d_ws;
    float* meanB   = bufY + 32LL * NN;
    float* z1      = meanB + 64LL * NN;
    float* z2      = z1 + 64LL * NN;
    float* z3      = z2 + 32LL * NN;
    float* inv_deg = z3 + NN;
    int* bcnt      = (int*)(inv_deg + NN);
    int* boffs     = bcnt + NB;
    int* bcursor   = boffs + NB + 1;
    int* row_ptr   = bcursor + NB;
    int* ssrc      = row_ptr + NN + 1;
    unsigned int* binned = (unsigned int*)z1;

    const int ntiles = (E + BT - 1) / BT;

    // ---- build dst-sorted CSR (dst identical across all 3 layers) ----
    (void)hipMemsetAsync(bcnt, 0, NB * sizeof(int), stream);
    bucket_hist_kernel<<<512, 256, 0, stream>>>(dst, bcnt, E);
    bucket_scan_kernel<<<1, 512, 0, stream>>>(bcnt, boffs, bcursor);
    bin_edges_kernel<<<ntiles, 512, 0, stream>>>(src, dst, bcursor, binned, E);
    csr_sort_kernel<<<NB, 1024, 0, stream>>>(binned, boffs, ssrc, row_ptr, inv_deg, NN, E);

    // ---- layer 1: y1 = x@W1l (fp8), z1 = x@W1r + b1 (MFMA) ----
    mlp_mfma_kernel<64, 64, 64, 128, 0><<<(NN + 127) / 128, 256, 0, stream>>>(
        x, nullptr, W1l, W1r, b1, (unsigned char*)bufY, z1, NN);
    agg_mean_fp8_kernel<64><<<(NN + 63) / 64, 256, 0, stream>>>(
        (const unsigned int*)bufY, row_ptr, ssrc, inv_deg, meanB, NN);

    // ---- layer 2: h1 = relu(mean1+z1) fused; y2 fp8, z2 (MFMA) ----
    mlp_mfma_kernel<64, 32, 32, 128, 1><<<(NN + 127) / 128, 256, 0, stream>>>(
        meanB, z1, W2l, W2r, b2, (unsigned char*)bufY, z2, NN);
    agg_mean_fp8_kernel<32><<<(NN + 127) / 128, 256, 0, stream>>>(
        (const unsigned int*)bufY, row_ptr, ssrc, inv_deg, meanB, NN);

    // ---- layer 3: h2 = relu(mean2+z2); y3 f32, z3 ----
    float* y3 = bufY;  // y2 dead after agg32
    mlp3_kernel<32><<<(NN + 255) / 256, 256, 0, stream>>>(
        meanB, z2, W3l, W3r, b3, y3, z3, NN);
    agg_mean_d1_kernel<<<(NN + 3) / 4, 256, 0, stream>>>(
        y3, row_ptr, ssrc, inv_deg, meanB, NN);
    sigmoid_out_kernel<<<(NN + 255) / 256, 256, 0, stream>>>(meanB, z3, out, NN);
}